// Round 1
// baseline (107.143 us; speedup 1.0000x reference)
//
#include <hip/hip_runtime.h>

// Problem constants (from reference)
#define S_DIM 28
#define B_BOX 2
#define C_CLS 20
#define D_CH 28            // = 4*B + C
#define BATCH_N 512
#define CELLS (BATCH_N * S_DIM * S_DIM)   // 401408
#define BLOCK 256
#define NBLOCKS (CELLS / BLOCK)           // 1568 (divides exactly)

// box channels: 0..3 and 24..27 ; cls channels: 8..27
// loss = (2*sum((p_box-t_box)^2) + sum(mask ? CE : 0)) / BATCH

__global__ __launch_bounds__(BLOCK) void yolo_cell_kernel(
    const float* __restrict__ preds,
    const float* __restrict__ tgts,
    float* __restrict__ partial)
{
    const int cell = blockIdx.x * BLOCK + threadIdx.x;   // grid sized exactly
    const float4* p4 = reinterpret_cast<const float4*>(preds + (size_t)cell * D_CH);
    const float4* t4 = reinterpret_cast<const float4*>(tgts  + (size_t)cell * D_CH);

    float p[D_CH], t[D_CH];
    #pragma unroll
    for (int i = 0; i < 7; ++i) {
        float4 a = p4[i];
        p[4*i+0] = a.x; p[4*i+1] = a.y; p[4*i+2] = a.z; p[4*i+3] = a.w;
    }
    #pragma unroll
    for (int i = 0; i < 7; ++i) {
        float4 b = t4[i];
        t[4*i+0] = b.x; t[4*i+1] = b.y; t[4*i+2] = b.z; t[4*i+3] = b.w;
    }

    // coord loss: channels 0..3 and 24..27
    float coord = 0.0f;
    #pragma unroll
    for (int j = 0; j < 4; ++j) {
        float d0 = p[j]      - t[j];      coord = fmaf(d0, d0, coord);
        float d1 = p[24 + j] - t[24 + j]; coord = fmaf(d1, d1, coord);
    }

    // class loss: channels 8..27
    float m    = -INFINITY;   // max of pred logits
    float tsum = 0.0f;        // sum of target cls (mask)
    float tmax = -INFINITY;   // argmax of target cls
    int   lab  = 0;
    #pragma unroll
    for (int j = 0; j < C_CLS; ++j) {
        float pc = p[8 + j];
        float tc = t[8 + j];
        m = fmaxf(m, pc);
        tsum += tc;
        if (tc > tmax) { tmax = tc; lab = j; }   // strict > keeps first max (jnp.argmax)
    }
    float se = 0.0f;
    #pragma unroll
    for (int j = 0; j < C_CLS; ++j) se += __expf(p[8 + j] - m);
    // pick p[8+lab] — lab is per-lane; small select chain after unroll
    float plab = p[8];
    #pragma unroll
    for (int j = 1; j < C_CLS; ++j) plab = (lab == j) ? p[8 + j] : plab;
    float ce = -(plab - m - __logf(se));

    float loss = 2.0f * coord + ((tsum > 0.0f) ? ce : 0.0f);

    // wave64 shuffle reduce
    #pragma unroll
    for (int off = 32; off > 0; off >>= 1) loss += __shfl_down(loss, off, 64);

    __shared__ float sm[BLOCK / 64];
    const int wid  = threadIdx.x >> 6;
    const int lane = threadIdx.x & 63;
    if (lane == 0) sm[wid] = loss;
    __syncthreads();
    if (threadIdx.x == 0) {
        float s = 0.0f;
        #pragma unroll
        for (int w = 0; w < BLOCK / 64; ++w) s += sm[w];
        partial[blockIdx.x] = s;
    }
}

__global__ __launch_bounds__(BLOCK) void yolo_final_kernel(
    const float* __restrict__ partial,
    float* __restrict__ out)
{
    float s = 0.0f;
    for (int i = threadIdx.x; i < NBLOCKS; i += BLOCK) s += partial[i];
    #pragma unroll
    for (int off = 32; off > 0; off >>= 1) s += __shfl_down(s, off, 64);

    __shared__ float sm[BLOCK / 64];
    const int wid  = threadIdx.x >> 6;
    const int lane = threadIdx.x & 63;
    if (lane == 0) sm[wid] = s;
    __syncthreads();
    if (threadIdx.x == 0) {
        float tot = 0.0f;
        #pragma unroll
        for (int w = 0; w < BLOCK / 64; ++w) tot += sm[w];
        out[0] = tot * (1.0f / (float)BATCH_N);
    }
}

extern "C" void kernel_launch(void* const* d_in, const int* in_sizes, int n_in,
                              void* d_out, int out_size, void* d_ws, size_t ws_size,
                              hipStream_t stream)
{
    const float* preds = (const float*)d_in[0];
    const float* tgts  = (const float*)d_in[1];
    float* out     = (float*)d_out;
    float* partial = (float*)d_ws;   // NBLOCKS floats = 6.1 KB

    yolo_cell_kernel<<<NBLOCKS, BLOCK, 0, stream>>>(preds, tgts, partial);
    yolo_final_kernel<<<1, BLOCK, 0, stream>>>(partial, out);
}